// Round 15
// baseline (53.270 us; speedup 1.0000x reference)
//
#include <hip/hip_runtime.h>
#include <math.h>

#define NRAYS 16384
#define NPTS  256
#define GS    160
#define GS2   (GS*GS)
#define GS3   (GS*GS*GS)

// ACT_SHIFT = log(1/(1-1e-6) - 1) computed in double precision
#define ACT_SHIFT (-13.815509557963774f)
#define LOG2E     (1.4426950408889634f)

typedef float floatx2 __attribute__((ext_vector_type(2)));

// pack 4 floats -> 4 fp8 e4m3 (OCP on gfx950) in one dword, HW RNE rounding
__device__ __forceinline__ unsigned int pack4fp8(float d, float r, float g, float b) {
    int w = __builtin_amdgcn_cvt_pk_fp8_f32(d, r, 0, false);   // bytes 0,1
    w     = __builtin_amdgcn_cvt_pk_fp8_f32(g, b, w, true);    // bytes 2,3
    return (unsigned int)w;
}

// unpack one corner word (4 fp8 channels), packed-f32 accumulate (v_pk_fma_f32)
__device__ __forceinline__ void acc2(unsigned int w, float cw,
                                     floatx2& sdr, floatx2& sgb) {
    floatx2 dr = __builtin_amdgcn_cvt_pk_f32_fp8((int)w, false);  // d, r
    floatx2 gb = __builtin_amdgcn_cvt_pk_f32_fp8((int)w, true);   // g, b
    floatx2 cw2 = {cw, cw};
    sdr += dr * cw2;
    sgb += gb * cw2;
}

// ---- repack: SoA f32 grids -> fp8 y-pair grid (8 B/voxel, 32.7 MB total) ----
__global__ __launch_bounds__(256)
void repack_fp8ypair_x4_kernel(const float* __restrict__ dgrid,
                               const float* __restrict__ cgrid,
                               uint4* __restrict__ out)   // 2 voxels per uint4
{
    const int c = blockIdx.x * 256 + threadIdx.x;    // chunk index, 4 voxels
    const int i = c * 4;
    if (i >= GS3) return;
    const int y  = (i / GS) % GS;
    const int dy = (y < GS - 1) ? GS : 0;            // +1 row (dup at edge)

    const float4 d0 = *reinterpret_cast<const float4*>(&dgrid[i]);
    const float4 r0 = *reinterpret_cast<const float4*>(&cgrid[i]);
    const float4 g0 = *reinterpret_cast<const float4*>(&cgrid[GS3 + i]);
    const float4 b0 = *reinterpret_cast<const float4*>(&cgrid[2*GS3 + i]);
    const float4 d1 = *reinterpret_cast<const float4*>(&dgrid[i + dy]);
    const float4 r1 = *reinterpret_cast<const float4*>(&cgrid[i + dy]);
    const float4 g1 = *reinterpret_cast<const float4*>(&cgrid[GS3 + i + dy]);
    const float4 b1 = *reinterpret_cast<const float4*>(&cgrid[2*GS3 + i + dy]);

    uint4 o0, o1;
    o0.x = pack4fp8(d0.x, r0.x, g0.x, b0.x);  o0.y = pack4fp8(d1.x, r1.x, g1.x, b1.x);
    o0.z = pack4fp8(d0.y, r0.y, g0.y, b0.y);  o0.w = pack4fp8(d1.y, r1.y, g1.y, b1.y);
    o1.x = pack4fp8(d0.z, r0.z, g0.z, b0.z);  o1.y = pack4fp8(d1.z, r1.z, g1.z, b1.z);
    o1.z = pack4fp8(d0.w, r0.w, g0.w, b0.w);  o1.w = pack4fp8(d1.w, r1.w, g1.w, b1.w);

    out[c*2 + 0] = o0;
    out[c*2 + 1] = o1;
}

// ---- sample: 8 rays/block, software-pipelined (issue ray i+1's gathers
// before consuming ray i's). All 8 t prefetched up front so no young vmem
// load forces draining in-flight gathers. Corner weights computed at issue
// time (overlaps the load). Stages fully unrolled -> constant indices.
__global__ __launch_bounds__(256)
void sample_fp8yp_pipe_kernel(const float* __restrict__ origins,
                              const float* __restrict__ directions,
                              const float* __restrict__ lengths,
                              const uint2* __restrict__ grid,
                              float* __restrict__ out_density,
                              float* __restrict__ out_color)
{
    const int tid   = threadIdx.x;
    const int r0    = blockIdx.x * 8;
    const int base0 = r0 * NPTS + tid;
    const float half_sm1 = 0.5f * (float)(GS - 1);

    // prefetch all 8 t values (coalesced dword loads, all in flight at once)
    float tv[8];
    #pragma unroll
    for (int i = 0; i < 8; ++i)
        tv[i] = __builtin_nontemporal_load(&lengths[base0 + i*NPTS]);

    uint4 e0[2], e1[2];
    float cw[2][8];
    float itv[2];

#define ISSUE(s, i) {                                                        \
    const int r = r0 + (i);                                                  \
    const float ox = origins[3*r+0], oy = origins[3*r+1], oz = origins[3*r+2]; \
    const float dx = directions[3*r+0], dy = directions[3*r+1], dz = directions[3*r+2]; \
    itv[s] = sqrtf(dx*dx + dy*dy + dz*dz);                                   \
    const float t  = tv[i];                                                  \
    const float px = (ox + dx*t + 1.0f) * half_sm1;                          \
    const float py = (oy + dy*t + 1.0f) * half_sm1;                          \
    const float pz = (oz + dz*t + 1.0f) * half_sm1;                          \
    const float fx = floorf(px), fy = floorf(py), fz = floorf(pz);           \
    const int x0 = min(max((int)fx, 0), GS-2);                               \
    const int y0 = min(max((int)fy, 0), GS-2);                               \
    const int z0 = min(max((int)fz, 0), GS-2);                               \
    const int i0 = (z0*GS + y0)*GS + x0;                                     \
    e0[s] = *reinterpret_cast<const uint4*>(&grid[i0]);                      \
    e1[s] = *reinterpret_cast<const uint4*>(&grid[i0 + GS2]);                \
    const float wx1 = px - fx, wy1 = py - fy, wz1 = pz - fz;                 \
    const float wx0 = 1.0f - wx1, wy0 = 1.0f - wy1, wz0 = 1.0f - wz1;        \
    const float c00 = wy0*wx0, c10 = wy1*wx0, c01 = wy0*wx1, c11 = wy1*wx1;  \
    cw[s][0] = wz0*c00; cw[s][1] = wz0*c10; cw[s][2] = wz0*c01; cw[s][3] = wz0*c11; \
    cw[s][4] = wz1*c00; cw[s][5] = wz1*c10; cw[s][6] = wz1*c01; cw[s][7] = wz1*c11; \
}

#define FINISH(s, i) {                                                       \
    floatx2 sdr = {0.f, 0.f}, sgb = {0.f, 0.f};                              \
    acc2(e0[s].x, cw[s][0], sdr, sgb);                                       \
    acc2(e0[s].y, cw[s][1], sdr, sgb);                                       \
    acc2(e0[s].z, cw[s][2], sdr, sgb);                                       \
    acc2(e0[s].w, cw[s][3], sdr, sgb);                                       \
    acc2(e1[s].x, cw[s][4], sdr, sgb);                                       \
    acc2(e1[s].y, cw[s][5], sdr, sgb);                                       \
    acc2(e1[s].z, cw[s][6], sdr, sgb);                                       \
    acc2(e1[s].w, cw[s][7], sdr, sgb);                                       \
    const float a  = sdr.x + ACT_SHIFT;                                      \
    const float ea = __builtin_amdgcn_exp2f(LOG2E * a);                      \
    const float L  = __builtin_amdgcn_logf(1.0f + ea);                       \
    const int  id  = base0 + (i)*NPTS;                                       \
    __builtin_nontemporal_store(1.0f - __builtin_amdgcn_exp2f(-itv[s] * L),  \
                                &out_density[id]);                           \
    const float x1 = __builtin_amdgcn_exp2f(-LOG2E * sdr.y);                 \
    const float x2 = __builtin_amdgcn_exp2f(-LOG2E * sgb.x);                 \
    const float x3 = __builtin_amdgcn_exp2f(-LOG2E * sgb.y);                 \
    float3 col;                                                              \
    col.x = __builtin_amdgcn_rcpf(1.0f + x1);                                \
    col.y = __builtin_amdgcn_rcpf(1.0f + x2);                                \
    col.z = __builtin_amdgcn_rcpf(1.0f + x3);                                \
    *reinterpret_cast<float3*>(&out_color[id*3]) = col;                      \
}

    ISSUE(0, 0);
    #pragma unroll
    for (int i = 0; i < 7; ++i) {
        ISSUE((i+1)&1, i+1);   // next ray's gathers in flight...
        FINISH(i&1, i);        // ...while this ray's math runs
    }
    FINISH(1, 7);

#undef ISSUE
#undef FINISH
}

// ---------------- fallback: direct SoA sampling (round-2 kernel) ----------------
__device__ __forceinline__ float2 ld2(const float* p) {
    return *reinterpret_cast<const float2*>(p);
}

__global__ __launch_bounds__(256)
void dvgo_render_kernel(const float* __restrict__ origins,
                        const float* __restrict__ directions,
                        const float* __restrict__ lengths,
                        const float* __restrict__ dgrid,
                        const float* __restrict__ cgrid,
                        float* __restrict__ out_density,
                        float* __restrict__ out_color)
{
    const int r = blockIdx.x;
    const int p = threadIdx.x;
    const int idx = r * NPTS + p;

    const float t  = lengths[idx];
    const float ox = origins[3*r+0], oy = origins[3*r+1], oz = origins[3*r+2];
    const float dx = directions[3*r+0], dy = directions[3*r+1], dz = directions[3*r+2];
    const float interval = sqrtf(dx*dx + dy*dy + dz*dz);

    const float x = ox + dx*t;
    const float y = oy + dy*t;
    const float z = oz + dz*t;

    const float half_sm1 = 0.5f * (float)(GS - 1);
    const float px = (x + 1.0f) * half_sm1;
    const float py = (y + 1.0f) * half_sm1;
    const float pz = (z + 1.0f) * half_sm1;

    const float fx = floorf(px), fy = floorf(py), fz = floorf(pz);
    const float wx1 = px - fx, wy1 = py - fy, wz1 = pz - fz;
    const float wx0 = 1.0f - wx1, wy0 = 1.0f - wy1, wz0 = 1.0f - wz1;

    int x0 = (int)fx, y0 = (int)fy, z0 = (int)fz;
    x0 = min(max(x0, 0), GS-2);
    y0 = min(max(y0, 0), GS-2);
    z0 = min(max(z0, 0), GS-2);

    int rows[4];
    rows[0] = ((z0  )*GS + y0  )*GS + x0;
    rows[1] = ((z0  )*GS + y0+1)*GS + x0;
    rows[2] = ((z0+1)*GS + y0  )*GS + x0;
    rows[3] = ((z0+1)*GS + y0+1)*GS + x0;

    const float* bases[4] = {dgrid, cgrid, cgrid + GS3, cgrid + 2*GS3};

    float2 v[4][4];
    #pragma unroll
    for (int ch = 0; ch < 4; ++ch)
        #pragma unroll
        for (int rr = 0; rr < 4; ++rr)
            v[ch][rr] = ld2(bases[ch] + rows[rr]);

    float rw[4];
    rw[0] = wz0*wy0; rw[1] = wz0*wy1; rw[2] = wz1*wy0; rw[3] = wz1*wy1;

    float s[4];
    #pragma unroll
    for (int ch = 0; ch < 4; ++ch) {
        float acc = 0.0f;
        #pragma unroll
        for (int rr = 0; rr < 4; ++rr)
            acc = fmaf(rw[rr], fmaf(v[ch][rr].x, wx0, v[ch][rr].y * wx1), acc);
        s[ch] = acc;
    }

    const float a  = s[0] + ACT_SHIFT;
    const float sp = (a > 20.0f) ? a : log1pf(__expf(a));
    out_density[idx] = 1.0f - __expf(-interval * sp);

    #pragma unroll
    for (int c = 0; c < 3; ++c)
        out_color[idx*3 + c] = 1.0f / (1.0f + __expf(-s[c+1]));
}

extern "C" void kernel_launch(void* const* d_in, const int* in_sizes, int n_in,
                              void* d_out, int out_size, void* d_ws, size_t ws_size,
                              hipStream_t stream) {
    const float* origins    = (const float*)d_in[0];
    const float* directions = (const float*)d_in[1];
    const float* lengths    = (const float*)d_in[2];
    const float* dgrid      = (const float*)d_in[3];
    const float* cgrid      = (const float*)d_in[4];

    float* out_density = (float*)d_out;               // [R, P, 1]
    float* out_color   = (float*)d_out + NRAYS*NPTS;  // [R, P, 3]

    if (ws_size >= (size_t)GS3 * sizeof(uint2)) {
        uint2* ypairs = (uint2*)d_ws;
        repack_fp8ypair_x4_kernel<<<(GS3/4 + 255) / 256, 256, 0, stream>>>(
            dgrid, cgrid, (uint4*)ypairs);
        sample_fp8yp_pipe_kernel<<<NRAYS / 8, 256, 0, stream>>>(
            origins, directions, lengths, ypairs, out_density, out_color);
    } else {
        dvgo_render_kernel<<<NRAYS, NPTS, 0, stream>>>(
            origins, directions, lengths, dgrid, cgrid, out_density, out_color);
    }
}

// Round 17
// 45.685 us; speedup vs baseline: 1.1660x; 1.1660x over previous
//
#include <hip/hip_runtime.h>
#include <math.h>

#define NRAYS 16384
#define NPTS  256
#define GS    160
#define GS2   (GS*GS)
#define GS3   (GS*GS*GS)

// ACT_SHIFT = log(1/(1-1e-6) - 1) computed in double precision
#define ACT_SHIFT (-13.815509557963774f)
#define LOG2E     (1.4426950408889634f)

typedef float floatx2 __attribute__((ext_vector_type(2)));

// pack 4 floats -> 4 fp8 e4m3 (OCP on gfx950) in one dword, HW RNE rounding
__device__ __forceinline__ unsigned int pack4fp8(float d, float r, float g, float b) {
    int w = __builtin_amdgcn_cvt_pk_fp8_f32(d, r, 0, false);   // bytes 0,1
    w     = __builtin_amdgcn_cvt_pk_fp8_f32(g, b, w, true);    // bytes 2,3
    return (unsigned int)w;
}

// unpack one corner word (4 fp8 channels), packed-f32 accumulate (v_pk_fma_f32)
__device__ __forceinline__ void acc2(unsigned int w, float cw,
                                     floatx2& sdr, floatx2& sgb) {
    floatx2 dr = __builtin_amdgcn_cvt_pk_f32_fp8((int)w, false);  // d, r
    floatx2 gb = __builtin_amdgcn_cvt_pk_f32_fp8((int)w, true);   // g, b
    floatx2 cw2 = {cw, cw};
    sdr += dr * cw2;
    sgb += gb * cw2;
}

// ---- repack: SoA f32 grids -> fp8 y-pair grid (8 B/voxel, 32.7 MB total) ----
// entry[z][y][x] = {d,r,g,b}(z,y,x) ++ {d,r,g,b}(z,y+1,x), fp8 each.
// 4 voxels/thread: 8 float4 loads + 2 uint4 stores per thread.
__global__ __launch_bounds__(256)
void repack_fp8ypair_x4_kernel(const float* __restrict__ dgrid,
                               const float* __restrict__ cgrid,
                               uint4* __restrict__ out)   // 2 voxels per uint4
{
    const int c = blockIdx.x * 256 + threadIdx.x;    // chunk index, 4 voxels
    const int i = c * 4;
    if (i >= GS3) return;
    const int y  = (i / GS) % GS;
    const int dy = (y < GS - 1) ? GS : 0;            // +1 row (dup at edge)

    const float4 d0 = *reinterpret_cast<const float4*>(&dgrid[i]);
    const float4 r0 = *reinterpret_cast<const float4*>(&cgrid[i]);
    const float4 g0 = *reinterpret_cast<const float4*>(&cgrid[GS3 + i]);
    const float4 b0 = *reinterpret_cast<const float4*>(&cgrid[2*GS3 + i]);
    const float4 d1 = *reinterpret_cast<const float4*>(&dgrid[i + dy]);
    const float4 r1 = *reinterpret_cast<const float4*>(&cgrid[i + dy]);
    const float4 g1 = *reinterpret_cast<const float4*>(&cgrid[GS3 + i + dy]);
    const float4 b1 = *reinterpret_cast<const float4*>(&cgrid[2*GS3 + i + dy]);

    uint4 o0, o1;
    o0.x = pack4fp8(d0.x, r0.x, g0.x, b0.x);  o0.y = pack4fp8(d1.x, r1.x, g1.x, b1.x);
    o0.z = pack4fp8(d0.y, r0.y, g0.y, b0.y);  o0.w = pack4fp8(d1.y, r1.y, g1.y, b1.y);
    o1.x = pack4fp8(d0.z, r0.z, g0.z, b0.z);  o1.y = pack4fp8(d1.z, r1.z, g1.z, b1.z);
    o1.z = pack4fp8(d0.w, r0.w, g0.w, b0.w);  o1.w = pack4fp8(d1.w, r1.w, g1.w, b1.w);

    out[c*2 + 0] = o0;
    out[c*2 + 1] = o1;
}

// one point's full pipeline after the gathers: interp + activations
__device__ __forceinline__ void finish_point(const uint4 ez0, const uint4 ez1,
                                             float px, float py, float pz,
                                             float fx, float fy, float fz,
                                             float interval,
                                             float& den, float& cr, float& cg, float& cb)
{
    const float wx1 = px - fx, wy1 = py - fy, wz1 = pz - fz;
    const float wx0 = 1.0f - wx1, wy0 = 1.0f - wy1, wz0 = 1.0f - wz1;
    const float c00 = wy0*wx0, c10 = wy1*wx0, c01 = wy0*wx1, c11 = wy1*wx1;

    floatx2 sdr = {0.f, 0.f}, sgb = {0.f, 0.f};
    acc2(ez0.x, wz0*c00, sdr, sgb);
    acc2(ez0.y, wz0*c10, sdr, sgb);
    acc2(ez0.z, wz0*c01, sdr, sgb);
    acc2(ez0.w, wz0*c11, sdr, sgb);
    acc2(ez1.x, wz1*c00, sdr, sgb);
    acc2(ez1.y, wz1*c10, sdr, sgb);
    acc2(ez1.z, wz1*c01, sdr, sgb);
    acc2(ez1.w, wz1*c11, sdr, sgb);

    // density = 1 - (1+e^a)^(-interval) = 1 - 2^(-interval * log2(1 + 2^(a*log2e)))
    const float a  = sdr.x + ACT_SHIFT;
    const float ea = __builtin_amdgcn_exp2f(LOG2E * a);
    const float L  = __builtin_amdgcn_logf(1.0f + ea);
    den = 1.0f - __builtin_amdgcn_exp2f(-interval * L);

    const float e1 = __builtin_amdgcn_exp2f(-LOG2E * sdr.y);
    const float e2 = __builtin_amdgcn_exp2f(-LOG2E * sgb.x);
    const float e3 = __builtin_amdgcn_exp2f(-LOG2E * sgb.y);
    cr = __builtin_amdgcn_rcpf(1.0f + e1);
    cg = __builtin_amdgcn_rcpf(1.0f + e2);
    cb = __builtin_amdgcn_rcpf(1.0f + e3);
}

// ---- sample: 2 points/thread, 2 rays/block (r14 structure -- empirical optimum
// over sort/ILPx4/8-ray-pipeline variants). 4 gathers in flight per thread,
// vectorized nt stores (write-once output kept out of L2 so the fp8 grid stays).
__global__ __launch_bounds__(256)
void sample_fp8yp_x2_kernel(const float* __restrict__ origins,
                            const float* __restrict__ directions,
                            const float* __restrict__ lengths,
                            const uint2* __restrict__ grid,
                            float* __restrict__ out_density,
                            float* __restrict__ out_color)
{
    const int tid  = threadIdx.x;
    const int half = tid >> 7;                 // 0/1: which ray of this block
    const int lh   = tid & 127;
    const int r    = blockIdx.x * 2 + half;
    const int base = r * NPTS;
    const int p0   = lh * 2;                   // even
    const int idx0 = base + p0;

    const float2 t2 = *reinterpret_cast<const float2*>(&lengths[idx0]);
    const float ox = origins[3*r+0], oy = origins[3*r+1], oz = origins[3*r+2];
    const float dx = directions[3*r+0], dy = directions[3*r+1], dz = directions[3*r+2];
    const float interval = sqrtf(dx*dx + dy*dy + dz*dz);
    const float half_sm1 = 0.5f * (float)(GS - 1);

    // addresses for both points first
    const float pxA = (ox + dx*t2.x + 1.0f) * half_sm1;
    const float pyA = (oy + dy*t2.x + 1.0f) * half_sm1;
    const float pzA = (oz + dz*t2.x + 1.0f) * half_sm1;
    const float pxB = (ox + dx*t2.y + 1.0f) * half_sm1;
    const float pyB = (oy + dy*t2.y + 1.0f) * half_sm1;
    const float pzB = (oz + dz*t2.y + 1.0f) * half_sm1;

    const float fxA = floorf(pxA), fyA = floorf(pyA), fzA = floorf(pzA);
    const float fxB = floorf(pxB), fyB = floorf(pyB), fzB = floorf(pzB);

    const int xA = min(max((int)fxA, 0), GS-2);
    const int yA = min(max((int)fyA, 0), GS-2);
    const int zA = min(max((int)fzA, 0), GS-2);
    const int xB = min(max((int)fxB, 0), GS-2);
    const int yB = min(max((int)fyB, 0), GS-2);
    const int zB = min(max((int)fzB, 0), GS-2);

    const int iA = (zA*GS + yA)*GS + xA;
    const int iB = (zB*GS + yB)*GS + xB;

    // 4 gathers in flight (16B each, 8B-aligned dwordx4)
    const uint4 eA0 = *reinterpret_cast<const uint4*>(&grid[iA]);
    const uint4 eA1 = *reinterpret_cast<const uint4*>(&grid[iA + GS2]);
    const uint4 eB0 = *reinterpret_cast<const uint4*>(&grid[iB]);
    const uint4 eB1 = *reinterpret_cast<const uint4*>(&grid[iB + GS2]);

    float denA, rA, gA, bA, denB, rB, gB, bB;
    finish_point(eA0, eA1, pxA, pyA, pzA, fxA, fyA, fzA, interval, denA, rA, gA, bA);
    finish_point(eB0, eB1, pxB, pyB, pzB, fxB, fyB, fzB, interval, denB, rB, gB, bB);

    // vectorized nt stores via ext-vector floatx2 (builtin rejects HIP float2 class)
    floatx2 den2 = {denA, denB};
    __builtin_nontemporal_store(den2, reinterpret_cast<floatx2*>(&out_density[idx0]));

    float* cp = &out_color[idx0 * 3];
    floatx2 c01 = {rA, gA};
    floatx2 c23 = {bA, rB};
    floatx2 c45 = {gB, bB};
    __builtin_nontemporal_store(c01, reinterpret_cast<floatx2*>(cp + 0));
    __builtin_nontemporal_store(c23, reinterpret_cast<floatx2*>(cp + 2));
    __builtin_nontemporal_store(c45, reinterpret_cast<floatx2*>(cp + 4));
}

// ---------------- fallback: direct SoA sampling (round-2 kernel) ----------------
__device__ __forceinline__ float2 ld2(const float* p) {
    return *reinterpret_cast<const float2*>(p);
}

__global__ __launch_bounds__(256)
void dvgo_render_kernel(const float* __restrict__ origins,
                        const float* __restrict__ directions,
                        const float* __restrict__ lengths,
                        const float* __restrict__ dgrid,
                        const float* __restrict__ cgrid,
                        float* __restrict__ out_density,
                        float* __restrict__ out_color)
{
    const int r = blockIdx.x;
    const int p = threadIdx.x;
    const int idx = r * NPTS + p;

    const float t  = lengths[idx];
    const float ox = origins[3*r+0], oy = origins[3*r+1], oz = origins[3*r+2];
    const float dx = directions[3*r+0], dy = directions[3*r+1], dz = directions[3*r+2];
    const float interval = sqrtf(dx*dx + dy*dy + dz*dz);

    const float x = ox + dx*t;
    const float y = oy + dy*t;
    const float z = oz + dz*t;

    const float half_sm1 = 0.5f * (float)(GS - 1);
    const float px = (x + 1.0f) * half_sm1;
    const float py = (y + 1.0f) * half_sm1;
    const float pz = (z + 1.0f) * half_sm1;

    const float fx = floorf(px), fy = floorf(py), fz = floorf(pz);
    const float wx1 = px - fx, wy1 = py - fy, wz1 = pz - fz;
    const float wx0 = 1.0f - wx1, wy0 = 1.0f - wy1, wz0 = 1.0f - wz1;

    int x0 = (int)fx, y0 = (int)fy, z0 = (int)fz;
    x0 = min(max(x0, 0), GS-2);
    y0 = min(max(y0, 0), GS-2);
    z0 = min(max(z0, 0), GS-2);

    int rows[4];
    rows[0] = ((z0  )*GS + y0  )*GS + x0;
    rows[1] = ((z0  )*GS + y0+1)*GS + x0;
    rows[2] = ((z0+1)*GS + y0  )*GS + x0;
    rows[3] = ((z0+1)*GS + y0+1)*GS + x0;

    const float* bases[4] = {dgrid, cgrid, cgrid + GS3, cgrid + 2*GS3};

    float2 v[4][4];
    #pragma unroll
    for (int ch = 0; ch < 4; ++ch)
        #pragma unroll
        for (int rr = 0; rr < 4; ++rr)
            v[ch][rr] = ld2(bases[ch] + rows[rr]);

    float rw[4];
    rw[0] = wz0*wy0; rw[1] = wz0*wy1; rw[2] = wz1*wy0; rw[3] = wz1*wy1;

    float s[4];
    #pragma unroll
    for (int ch = 0; ch < 4; ++ch) {
        float acc = 0.0f;
        #pragma unroll
        for (int rr = 0; rr < 4; ++rr)
            acc = fmaf(rw[rr], fmaf(v[ch][rr].x, wx0, v[ch][rr].y * wx1), acc);
        s[ch] = acc;
    }

    const float a  = s[0] + ACT_SHIFT;
    const float sp = (a > 20.0f) ? a : log1pf(__expf(a));
    out_density[idx] = 1.0f - __expf(-interval * sp);

    #pragma unroll
    for (int c = 0; c < 3; ++c)
        out_color[idx*3 + c] = 1.0f / (1.0f + __expf(-s[c+1]));
}

extern "C" void kernel_launch(void* const* d_in, const int* in_sizes, int n_in,
                              void* d_out, int out_size, void* d_ws, size_t ws_size,
                              hipStream_t stream) {
    const float* origins    = (const float*)d_in[0];
    const float* directions = (const float*)d_in[1];
    const float* lengths    = (const float*)d_in[2];
    const float* dgrid      = (const float*)d_in[3];
    const float* cgrid      = (const float*)d_in[4];

    float* out_density = (float*)d_out;               // [R, P, 1]
    float* out_color   = (float*)d_out + NRAYS*NPTS;  // [R, P, 3]

    if (ws_size >= (size_t)GS3 * sizeof(uint2)) {
        uint2* ypairs = (uint2*)d_ws;
        repack_fp8ypair_x4_kernel<<<(GS3/4 + 255) / 256, 256, 0, stream>>>(
            dgrid, cgrid, (uint4*)ypairs);
        sample_fp8yp_x2_kernel<<<NRAYS / 2, 256, 0, stream>>>(
            origins, directions, lengths, ypairs, out_density, out_color);
    } else {
        dvgo_render_kernel<<<NRAYS, NPTS, 0, stream>>>(
            origins, directions, lengths, dgrid, cgrid, out_density, out_color);
    }
}